// Round 2
// baseline (1607.754 us; speedup 1.0000x reference)
//
#include <hip/hip_runtime.h>
#include <hip/hip_bf16.h>

#define NA 4096
#define DD 256
#define HH 4
#define CC 64
#define LL 2
#define TOPK 5

typedef __hip_bfloat16 bf16;

__device__ __forceinline__ float b2f(bf16 v) { return __bfloat162float(v); }
__device__ __forceinline__ float u2f(unsigned int u) { union { unsigned int i; float f; } x; x.i = u; return x.f; }
__device__ __forceinline__ float ldx(const void* p, size_t i, int bfm) {
  return bfm ? b2f(((const bf16*)p)[i]) : ((const float*)p)[i];
}

// ---------------- dtype detect: bf16 vs fp32 ----------------
__global__ __launch_bounds__(256) void k_detect(const void* probe, int* flag) {
  __shared__ int cnt;
  if (threadIdx.x == 0) cnt = 0;
  __syncthreads();
  const unsigned short* u = (const unsigned short*)probe;
  int bad = 0;
  for (int i = threadIdx.x; i < 2048; i += 256) {
    float v = u2f(((unsigned int)u[i]) << 16);
    if (!(fabsf(v) <= 1e10f)) bad++;
  }
  atomicAdd(&cnt, bad);
  __syncthreads();
  if (threadIdx.x == 0) flag[0] = (cnt < 64) ? 1 : 0;
}

// ---------------- prep ----------------
__global__ __launch_bounds__(256) void k_prep(
    const void* __restrict__ st, const void* __restrict__ em, const void* __restrict__ ro,
    const int* __restrict__ flag,
    float* __restrict__ statesF, float* __restrict__ enh, float* __restrict__ nsm)
{
  int i = blockIdx.x, d = threadIdx.x;
  int bfm = flag[0];
  __shared__ float red[256];
  float s = ldx(st, (size_t)i*DD + d, bfm);
  statesF[i*DD + d] = s;
  float e = s + ldx(em, (size_t)i*DD + d, bfm) + ldx(ro, (size_t)i*64 + (d & 63), bfm);
  enh[i*DD + d] = e;
  red[d] = e * e;
  __syncthreads();
  for (int k = 128; k > 0; k >>= 1) { if (d < k) red[d] += red[d + k]; __syncthreads(); }
  float inv = 1.0f / fmaxf(sqrtf(red[0]), 1e-12f);
  nsm[i*DD + d] = e * inv;
}

// ---------------- cosine sim + top-5 + adjacency bitset ----------------
__global__ __launch_bounds__(128) void k_simtopk(
    const float* __restrict__ nsm, unsigned long long* __restrict__ maskbits)
{
  __shared__ float At[32][20];
  __shared__ float Bs[32][132];
  __shared__ float simt[16][132];
  __shared__ float tval[16][TOPK];
  __shared__ int   tidn[16][TOPK];
  int tid = threadIdx.x;
  int ib = blockIdx.x * 16;
  int tr = tid >> 5, tc = tid & 31;
  if (tid < 16*TOPK) { tval[tid/TOPK][tid%TOPK] = -1e30f; tidn[tid/TOPK][tid%TOPK] = 0; }
  __syncthreads();
  for (int jb = 0; jb < NA; jb += 128) {
    float acc[4][4] = {{0.f,0.f,0.f,0.f},{0.f,0.f,0.f,0.f},{0.f,0.f,0.f,0.f},{0.f,0.f,0.f,0.f}};
    for (int kt = 0; kt < DD; kt += 32) {
      __syncthreads();
      {
        int r = tid >> 3, k4 = (tid & 7) * 4;
        float4 v = *(const float4*)&nsm[(size_t)(ib + r)*DD + kt + k4];
        At[k4+0][r] = v.x; At[k4+1][r] = v.y; At[k4+2][r] = v.z; At[k4+3][r] = v.w;
      }
      {
        const float4* src = (const float4*)&nsm[(size_t)(jb + tid)*DD + kt];
        #pragma unroll
        for (int q = 0; q < 8; q++) {
          float4 v = src[q];
          Bs[q*4+0][tid] = v.x; Bs[q*4+1][tid] = v.y; Bs[q*4+2][tid] = v.z; Bs[q*4+3][tid] = v.w;
        }
      }
      __syncthreads();
      #pragma unroll
      for (int kk = 0; kk < 32; kk++) {
        float4 av = *(float4*)&At[kk][tr*4];
        float4 bv = *(float4*)&Bs[kk][tc*4];
        acc[0][0] += av.x*bv.x; acc[0][1] += av.x*bv.y; acc[0][2] += av.x*bv.z; acc[0][3] += av.x*bv.w;
        acc[1][0] += av.y*bv.x; acc[1][1] += av.y*bv.y; acc[1][2] += av.y*bv.z; acc[1][3] += av.y*bv.w;
        acc[2][0] += av.z*bv.x; acc[2][1] += av.z*bv.y; acc[2][2] += av.z*bv.z; acc[2][3] += av.z*bv.w;
        acc[3][0] += av.w*bv.x; acc[3][1] += av.w*bv.y; acc[3][2] += av.w*bv.z; acc[3][3] += av.w*bv.w;
      }
    }
    #pragma unroll
    for (int i = 0; i < 4; i++) {
      float4 o; o.x = acc[i][0]; o.y = acc[i][1]; o.z = acc[i][2]; o.w = acc[i][3];
      *(float4*)&simt[tr*4 + i][tc*4] = o;
    }
    __syncthreads();
    if (tid < 16) {
      int r = tid;
      for (int c = 0; c < 128; c++) {
        float v = simt[r][c];
        if (v > tval[r][TOPK-1]) {
          int p = TOPK - 1;
          while (p > 0 && v > tval[r][p-1]) p--;
          for (int q = TOPK - 1; q > p; q--) { tval[r][q] = tval[r][q-1]; tidn[r][q] = tidn[r][q-1]; }
          tval[r][p] = v; tidn[r][p] = jb + c;
        }
      }
    }
    __syncthreads();
  }
  if (tid < 16) {
    int i = ib + tid;
    atomicOr(&maskbits[(size_t)i*64 + (i >> 6)], 1ull << (i & 63));
    #pragma unroll
    for (int k = 0; k < TOPK; k++) {
      int j = tidn[tid][k];
      atomicOr(&maskbits[(size_t)i*64 + (j >> 6)], 1ull << (j & 63));
      atomicOr(&maskbits[(size_t)j*64 + (i >> 6)], 1ull << (i & 63));
    }
  }
}

// ---------------- generic fp32 x (bf16|fp32) GEMM with elem offset ----------------
__global__ __launch_bounds__(256) void k_gemm(
    const float* __restrict__ Aim, const void* __restrict__ Bw, long boff,
    const void* __restrict__ bias, const float* __restrict__ resid,
    const int* __restrict__ flag,
    float* __restrict__ Cf, void* __restrict__ Cb,
    int M, int N, int Kd, int act, int accF)
{
  __shared__ float As[16][68];
  __shared__ float Bsh[16][68];
  int bfm = flag[0];
  int tid = threadIdx.x;
  int tx = tid & 15, ty = tid >> 4;
  int n0 = blockIdx.x * 64, m0 = blockIdx.y * 64;
  float acc[4][4] = {{0.f,0.f,0.f,0.f},{0.f,0.f,0.f,0.f},{0.f,0.f,0.f,0.f},{0.f,0.f,0.f,0.f}};
  for (int k0 = 0; k0 < Kd; k0 += 16) {
    {
      int ar = tid >> 2, kq = (tid & 3) * 4;
      float4 v = *(const float4*)&Aim[(size_t)(m0 + ar)*Kd + k0 + kq];
      As[kq+0][ar] = v.x; As[kq+1][ar] = v.y; As[kq+2][ar] = v.z; As[kq+3][ar] = v.w;
    }
    {
      int br = tid >> 4, nq = (tid & 15) * 4;
      int n = n0 + nq;
      float f0 = 0.f, f1 = 0.f, f2 = 0.f, f3 = 0.f;
      if (n < N) {
        size_t idx = (size_t)boff + (size_t)(k0 + br)*N + n;
        if (bfm) {
          uint2 raw = *(const uint2*)((const bf16*)Bw + idx);
          f0 = u2f(raw.x << 16); f1 = u2f(raw.x & 0xffff0000u);
          f2 = u2f(raw.y << 16); f3 = u2f(raw.y & 0xffff0000u);
        } else {
          float4 v = *(const float4*)((const float*)Bw + idx);
          f0 = v.x; f1 = v.y; f2 = v.z; f3 = v.w;
        }
      }
      Bsh[br][nq+0] = f0; Bsh[br][nq+1] = f1; Bsh[br][nq+2] = f2; Bsh[br][nq+3] = f3;
    }
    __syncthreads();
    #pragma unroll
    for (int kk = 0; kk < 16; kk++) {
      float4 av = *(float4*)&As[kk][ty*4];
      float4 bv = *(float4*)&Bsh[kk][tx*4];
      acc[0][0] += av.x*bv.x; acc[0][1] += av.x*bv.y; acc[0][2] += av.x*bv.z; acc[0][3] += av.x*bv.w;
      acc[1][0] += av.y*bv.x; acc[1][1] += av.y*bv.y; acc[1][2] += av.y*bv.z; acc[1][3] += av.y*bv.w;
      acc[2][0] += av.z*bv.x; acc[2][1] += av.z*bv.y; acc[2][2] += av.z*bv.z; acc[2][3] += av.z*bv.w;
      acc[3][0] += av.w*bv.x; acc[3][1] += av.w*bv.y; acc[3][2] += av.w*bv.z; acc[3][3] += av.w*bv.w;
    }
    __syncthreads();
  }
  #pragma unroll
  for (int i = 0; i < 4; i++) {
    int row = m0 + ty*4 + i;
    #pragma unroll
    for (int j = 0; j < 4; j++) {
      int col = n0 + tx*4 + j;
      if (col >= N) continue;
      size_t idx = (size_t)row*N + col;
      float v = acc[i][j];
      if (accF) v += Cf[idx];
      if (bias) v += ldx(bias, col, bfm);
      if (act == 1) v = fmaxf(v, 0.0f);
      if (resid) v += resid[idx];
      if (Cb) {
        if (bfm) ((bf16*)Cb)[idx] = __float2bfloat16(v);
        else ((float*)Cb)[idx] = v;
      } else Cf[idx] = v;
    }
  }
}

// ---------------- a_s, a_d ----------------
__global__ __launch_bounds__(256) void k_asd(
    const float* __restrict__ xs, const void* __restrict__ asrc, const void* __restrict__ adst,
    long loff, const int* __restrict__ flag,
    float* __restrict__ aS, float* __restrict__ aD)
{
  int i = blockIdx.x, t = threadIdx.x;
  int bfm = flag[0];
  __shared__ float rs[256], rd[256];
  float xv = xs[(size_t)i*DD + t];
  rs[t] = xv * ldx(asrc, loff + t, bfm);
  rd[t] = xv * ldx(adst, loff + t, bfm);
  __syncthreads();
  for (int k = 32; k > 0; k >>= 1) {
    if ((t & 63) < k) { rs[t] += rs[t + k]; rd[t] += rd[t + k]; }
    __syncthreads();
  }
  if ((t & 63) == 0) { int h = t >> 6; aS[i*HH + h] = rs[t]; aD[i*HH + h] = rd[t]; }
}

// ---------------- GAT aggregation + bias + LN + residual ----------------
__global__ __launch_bounds__(256) void k_gatagg(
    const float* __restrict__ xs, const float* __restrict__ aS, const float* __restrict__ aD,
    const unsigned long long* __restrict__ maskbits,
    const void* __restrict__ gbias, const void* __restrict__ lng, const void* __restrict__ lnb,
    long loff, const int* __restrict__ flag,
    const float* __restrict__ xold, float* __restrict__ xnew)
{
  __shared__ int nbr[NA];
  __shared__ float alph[NA];
  __shared__ float red[256];
  __shared__ float outv[DD];
  __shared__ int offs[64];
  __shared__ int degS;
  int j = blockIdx.x, t = threadIdx.x;
  int bfm = flag[0];
  unsigned long long bits = 0;
  if (t < 64) { bits = maskbits[(size_t)j*64 + t]; offs[t] = __popcll(bits); }
  __syncthreads();
  if (t == 0) { int run = 0; for (int w = 0; w < 64; w++) { int c = offs[w]; offs[w] = run; run += c; } degS = run; }
  __syncthreads();
  if (t < 64) {
    int base = offs[t];
    unsigned long long b = bits;
    while (b) { int p = __builtin_ctzll(b); nbr[base++] = t*64 + p; b &= b - 1; }
  }
  __syncthreads();
  int deg = degS;
  for (int h = 0; h < HH; h++) {
    float adjv = aD[j*HH + h];
    float lm = -1e30f;
    for (int n = t; n < deg; n += 256) {
      float lg = aS[nbr[n]*HH + h] + adjv;
      lg = (lg >= 0.f) ? lg : 0.2f*lg;
      alph[n] = lg;
      lm = fmaxf(lm, lg);
    }
    red[t] = lm; __syncthreads();
    for (int k = 128; k > 0; k >>= 1) { if (t < k) red[t] = fmaxf(red[t], red[t + k]); __syncthreads(); }
    float Mx = red[0];
    __syncthreads();
    float ls = 0.f;
    for (int n = t; n < deg; n += 256) { float w = __expf(alph[n] - Mx); alph[n] = w; ls += w; }
    red[t] = ls; __syncthreads();
    for (int k = 128; k > 0; k >>= 1) { if (t < k) red[t] += red[t + k]; __syncthreads(); }
    float Z = red[0];
    __syncthreads();
    int c = t & 63, q = t >> 6;
    float a2 = 0.f;
    for (int n = q; n < deg; n += 4) a2 += alph[n] * xs[(size_t)nbr[n]*DD + h*CC + c];
    red[t] = a2; __syncthreads();
    if (q == 0) outv[h*CC + c] = (red[c] + red[c+64] + red[c+128] + red[c+192]) / Z;
    __syncthreads();
  }
  float v = outv[t] + ldx(gbias, loff + t, bfm);
  red[t] = v; __syncthreads();
  for (int k = 128; k > 0; k >>= 1) { if (t < k) red[t] += red[t + k]; __syncthreads(); }
  float mu = red[0] * (1.0f/DD);
  __syncthreads();
  float dv = v - mu;
  red[t] = dv*dv; __syncthreads();
  for (int k = 128; k > 0; k >>= 1) { if (t < k) red[t] += red[t + k]; __syncthreads(); }
  float var = red[0] * (1.0f/DD);
  float xn = ldx(lng, loff + t, bfm) * dv * rsqrtf(var + 1e-5f) + ldx(lnb, loff + t, bfm) + xold[(size_t)j*DD + t];
  xnew[(size_t)j*DD + t] = xn;
}

// ---------------- flash-style MHA ----------------
__global__ __launch_bounds__(128) void k_mha(const float* __restrict__ qkv, float* __restrict__ ctx)
{
  __shared__ float QsT[64][36];
  __shared__ float KsT[64][68];
  __shared__ float Vs[64][68];
  __shared__ float SsT[64][36];
  int tid = threadIdx.x;
  int h = blockIdx.y;
  int q0 = blockIdx.x * 32;
  int tr = tid >> 4, tc = tid & 15;
  {
    int r = tid >> 2, c16 = (tid & 3) * 16;
    const float* qp = &qkv[(size_t)(q0 + r)*768 + h*64 + c16];
    #pragma unroll
    for (int q = 0; q < 4; q++) {
      float4 v = *(const float4*)(qp + q*4);
      QsT[c16 + q*4 + 0][r] = v.x; QsT[c16 + q*4 + 1][r] = v.y;
      QsT[c16 + q*4 + 2][r] = v.z; QsT[c16 + q*4 + 3][r] = v.w;
    }
  }
  float m[4] = {-1e30f,-1e30f,-1e30f,-1e30f};
  float l[4] = {0.f,0.f,0.f,0.f};
  float acc[4][4] = {{0.f,0.f,0.f,0.f},{0.f,0.f,0.f,0.f},{0.f,0.f,0.f,0.f},{0.f,0.f,0.f,0.f}};
  for (int kt = 0; kt < NA; kt += 64) {
    __syncthreads();
    {
      int rr = tid >> 1, c32 = (tid & 1) * 32;
      const float* kp = &qkv[(size_t)(kt + rr)*768 + 256 + h*64 + c32];
      const float* vp = kp + 256;
      #pragma unroll
      for (int q = 0; q < 8; q++) {
        float4 kv = *(const float4*)(kp + q*4);
        KsT[c32 + q*4 + 0][rr] = kv.x; KsT[c32 + q*4 + 1][rr] = kv.y;
        KsT[c32 + q*4 + 2][rr] = kv.z; KsT[c32 + q*4 + 3][rr] = kv.w;
        *(float4*)&Vs[rr][c32 + q*4] = *(const float4*)(vp + q*4);
      }
    }
    __syncthreads();
    float s[4][4] = {{0.f,0.f,0.f,0.f},{0.f,0.f,0.f,0.f},{0.f,0.f,0.f,0.f},{0.f,0.f,0.f,0.f}};
    #pragma unroll 8
    for (int d = 0; d < 64; d++) {
      float4 av = *(float4*)&QsT[d][tr*4];
      float4 bv = *(float4*)&KsT[d][tc*4];
      s[0][0] += av.x*bv.x; s[0][1] += av.x*bv.y; s[0][2] += av.x*bv.z; s[0][3] += av.x*bv.w;
      s[1][0] += av.y*bv.x; s[1][1] += av.y*bv.y; s[1][2] += av.y*bv.z; s[1][3] += av.y*bv.w;
      s[2][0] += av.z*bv.x; s[2][1] += av.z*bv.y; s[2][2] += av.z*bv.z; s[2][3] += av.z*bv.w;
      s[3][0] += av.w*bv.x; s[3][1] += av.w*bv.y; s[3][2] += av.w*bv.z; s[3][3] += av.w*bv.w;
    }
    #pragma unroll
    for (int i = 0; i < 4; i++) {
      #pragma unroll
      for (int q = 0; q < 4; q++) s[i][q] *= 0.125f;
      float rm = fmaxf(fmaxf(s[i][0], s[i][1]), fmaxf(s[i][2], s[i][3]));
      #pragma unroll
      for (int off = 1; off < 16; off <<= 1) rm = fmaxf(rm, __shfl_xor(rm, off, 16));
      float mn = fmaxf(m[i], rm);
      float corr = __expf(m[i] - mn);
      float p0 = __expf(s[i][0] - mn), p1 = __expf(s[i][1] - mn);
      float p2 = __expf(s[i][2] - mn), p3 = __expf(s[i][3] - mn);
      float ps = p0 + p1 + p2 + p3;
      #pragma unroll
      for (int off = 1; off < 16; off <<= 1) ps += __shfl_xor(ps, off, 16);
      m[i] = mn;
      l[i] = l[i]*corr + ps;
      acc[i][0] *= corr; acc[i][1] *= corr; acc[i][2] *= corr; acc[i][3] *= corr;
      SsT[tc*4 + 0][tr*4 + i] = p0; SsT[tc*4 + 1][tr*4 + i] = p1;
      SsT[tc*4 + 2][tr*4 + i] = p2; SsT[tc*4 + 3][tr*4 + i] = p3;
    }
    __syncthreads();
    #pragma unroll 4
    for (int jj = 0; jj < 64; jj++) {
      float4 pv = *(float4*)&SsT[jj][tr*4];
      float4 vv = *(float4*)&Vs[jj][tc*4];
      acc[0][0] += pv.x*vv.x; acc[0][1] += pv.x*vv.y; acc[0][2] += pv.x*vv.z; acc[0][3] += pv.x*vv.w;
      acc[1][0] += pv.y*vv.x; acc[1][1] += pv.y*vv.y; acc[1][2] += pv.y*vv.z; acc[1][3] += pv.y*vv.w;
      acc[2][0] += pv.z*vv.x; acc[2][1] += pv.z*vv.y; acc[2][2] += pv.z*vv.z; acc[2][3] += pv.z*vv.w;
      acc[3][0] += pv.w*vv.x; acc[3][1] += pv.w*vv.y; acc[3][2] += pv.w*vv.z; acc[3][3] += pv.w*vv.w;
    }
  }
  #pragma unroll
  for (int i = 0; i < 4; i++) {
    float inv = 1.0f / l[i];
    float4 o; o.x = acc[i][0]*inv; o.y = acc[i][1]*inv; o.z = acc[i][2]*inv; o.w = acc[i][3]*inv;
    *(float4*)&ctx[(size_t)(q0 + tr*4 + i)*DD + h*CC + tc*4] = o;
  }
}

// ---------------- gate ----------------
__global__ __launch_bounds__(256) void k_gate(
    const float* __restrict__ g1, const void* __restrict__ w2, const void* __restrict__ b2v,
    const int* __restrict__ flag,
    const float* __restrict__ agg, float* __restrict__ ag2)
{
  int i = blockIdx.x, t = threadIdx.x;
  int bfm = flag[0];
  __shared__ float red[256];
  red[t] = g1[(size_t)i*DD + t] * ldx(w2, t, bfm);
  __syncthreads();
  for (int k = 128; k > 0; k >>= 1) { if (t < k) red[t] += red[t + k]; __syncthreads(); }
  float sr = red[0] + ldx(b2v, 0, bfm);
  float s = 1.0f / (1.0f + __expf(-sr));
  ag2[(size_t)i*DD + t] = agg[(size_t)i*DD + t] * s;
}

extern "C" void kernel_launch(void* const* d_in, const int* in_sizes, int n_in,
                              void* d_out, int out_size, void* d_ws, size_t ws_size,
                              hipStream_t stream) {
  (void)in_sizes; (void)n_in; (void)out_size; (void)ws_size;
  const void* agent_states = d_in[0];
  const void* agent_emb    = d_in[1];
  const void* role_emb     = d_in[2];
  const void* gat_W        = d_in[3];
  const void* gat_att_src  = d_in[4];
  const void* gat_att_dst  = d_in[5];
  const void* gat_bias     = d_in[6];
  const void* ln_gamma     = d_in[7];
  const void* ln_beta      = d_in[8];
  const void* enc_W1 = d_in[9];
  const void* enc_b1 = d_in[10];
  const void* enc_W2 = d_in[11];
  const void* enc_b2 = d_in[12];
  const void* dec_W1 = d_in[13];
  const void* dec_b1 = d_in[14];
  const void* dec_W2 = d_in[15];
  const void* dec_b2 = d_in[16];
  const void* mha_in_w  = d_in[17];
  const void* mha_in_b  = d_in[18];
  const void* mha_out_w = d_in[19];
  const void* mha_out_b = d_in[20];
  const void* proj_W = d_in[21];
  const void* proj_b = d_in[22];
  const void* gate_W1 = d_in[23];
  const void* gate_b1 = d_in[24];
  const void* gate_W2 = d_in[25];
  const void* gate_b2 = d_in[26];

  char* base = (char*)d_ws;
  size_t off = 0;
  auto alloc = [&](size_t nbytes) -> char* {
    char* p = base + off; off += (nbytes + 255) & ~(size_t)255; return p;
  };
  int* flag = (int*)alloc(256);
  float* statesF = (float*)alloc((size_t)NA*DD*4);
  float* enh     = (float*)alloc((size_t)NA*DD*4);
  float* nsb     = (float*)alloc((size_t)NA*DD*4);
  unsigned long long* maskbits = (unsigned long long*)alloc((size_t)NA*64*8);
  float* xs  = (float*)alloc((size_t)NA*DD*4);
  float* xB  = (float*)alloc((size_t)NA*DD*4);
  float* qkv = (float*)alloc((size_t)NA*3*DD*4);
  float* dec = (float*)alloc((size_t)NA*DD*4);
  float* agg = (float*)alloc((size_t)NA*DD*4);
  float* xC  = enh;
  float* aS  = nsb;
  float* aD  = nsb + NA*HH;
  float* h1  = nsb + 2*NA*HH;
  float* msg = h1 + (size_t)NA*64;
  float* dh  = msg + (size_t)NA*32;
  float* ctx = dec;
  float* g1  = xs;
  float* ag2 = xB;

  auto gemm = [&](const float* A, const void* B, long boff, const void* bias, const float* resid,
                  float* Cf, void* Cb, int M, int Nn, int Kd, int act, int accF) {
    dim3 g((Nn + 63)/64, M/64);
    hipLaunchKernelGGL(k_gemm, g, dim3(256), 0, stream, A, B, boff, bias, resid, flag, Cf, Cb, M, Nn, Kd, act, accF);
  };

  hipMemsetAsync(maskbits, 0, (size_t)NA*64*8, stream);
  hipLaunchKernelGGL(k_detect, dim3(1), dim3(256), 0, stream, agent_states, flag);
  hipLaunchKernelGGL(k_prep, dim3(NA), dim3(256), 0, stream,
                     agent_states, agent_emb, role_emb, flag, statesF, enh, nsb);
  hipLaunchKernelGGL(k_simtopk, dim3(NA/16), dim3(128), 0, stream, nsb, maskbits);

  const float* xin = enh;
  float* xout = xB;
  for (int l = 0; l < LL; l++) {
    gemm(xin, gat_W, (long)l*DD*DD, nullptr, nullptr, xs, nullptr, NA, DD, DD, 0, 0);
    hipLaunchKernelGGL(k_asd, dim3(NA), dim3(256), 0, stream,
                       xs, gat_att_src, gat_att_dst, (long)l*DD, flag, aS, aD);
    hipLaunchKernelGGL(k_gatagg, dim3(NA), dim3(256), 0, stream,
                       xs, aS, aD, maskbits, gat_bias, ln_gamma, ln_beta, (long)l*DD, flag, xin, xout);
    xin = xout; xout = xC;
  }
  gemm(xin, enc_W1, 0, enc_b1, nullptr, h1, nullptr, NA, 64, DD, 1, 0);
  gemm(h1, enc_W2, 0, enc_b2, nullptr, msg, nullptr, NA, 32, 64, 0, 0);
  gemm(msg, dec_W1, 0, dec_b1, nullptr, dh, nullptr, NA, 128, 32, 1, 0);
  gemm(dh, dec_W2, 0, dec_b2, nullptr, dec, nullptr, NA, DD, 128, 0, 0);
  gemm(dec, mha_in_w, 0, mha_in_b, nullptr, qkv, nullptr, NA, 3*DD, DD, 0, 0);
  hipLaunchKernelGGL(k_mha, dim3(NA/32, HH), dim3(128), 0, stream, qkv, ctx);
  gemm(ctx, mha_out_w, 0, mha_out_b, nullptr, agg, nullptr, NA, DD, DD, 0, 0);
  gemm(statesF, gate_W1, 0, nullptr, nullptr, g1, nullptr, NA, DD, DD, 0, 0);
  gemm(agg, gate_W1, (long)DD*DD, gate_b1, nullptr, g1, nullptr, NA, DD, DD, 1, 1);
  hipLaunchKernelGGL(k_gate, dim3(NA), dim3(256), 0, stream, g1, gate_W2, gate_b2, flag, agg, ag2);
  gemm(ag2, proj_W, 0, proj_b, statesF, nullptr, d_out, NA, DD, DD, 0, 0);
}

// Round 3
// 1065.347 us; speedup vs baseline: 1.5091x; 1.5091x over previous
//
#include <hip/hip_runtime.h>
#include <hip/hip_bf16.h>

#define NA 4096
#define DD 256
#define HH 4
#define CC 64
#define LL 2
#define TOPK 5

typedef __hip_bfloat16 bf16;

__device__ __forceinline__ float b2f(bf16 v) { return __bfloat162float(v); }
__device__ __forceinline__ float u2f(unsigned int u) { union { unsigned int i; float f; } x; x.i = u; return x.f; }
__device__ __forceinline__ float ldx(const void* p, size_t i, int bfm) {
  return bfm ? b2f(((const bf16*)p)[i]) : ((const float*)p)[i];
}
// strict ordering used by jax.lax.top_k: larger value first, ties -> smaller index
__device__ __forceinline__ bool kbetter(float v, int c, float v2, int c2) {
  return (v > v2) || (v == v2 && c < c2);
}

// ---------------- dtype detect: bf16 vs fp32 ----------------
__global__ __launch_bounds__(256) void k_detect(const void* probe, int* flag) {
  __shared__ int cnt;
  if (threadIdx.x == 0) cnt = 0;
  __syncthreads();
  const unsigned short* u = (const unsigned short*)probe;
  int bad = 0;
  for (int i = threadIdx.x; i < 2048; i += 256) {
    float v = u2f(((unsigned int)u[i]) << 16);
    if (!(fabsf(v) <= 1e10f)) bad++;
  }
  atomicAdd(&cnt, bad);
  __syncthreads();
  if (threadIdx.x == 0) flag[0] = (cnt < 64) ? 1 : 0;
}

// ---------------- prep ----------------
__global__ __launch_bounds__(256) void k_prep(
    const void* __restrict__ st, const void* __restrict__ em, const void* __restrict__ ro,
    const int* __restrict__ flag,
    float* __restrict__ statesF, float* __restrict__ enh, float* __restrict__ nsm)
{
  int i = blockIdx.x, d = threadIdx.x;
  int bfm = flag[0];
  __shared__ float red[256];
  float s = ldx(st, (size_t)i*DD + d, bfm);
  statesF[i*DD + d] = s;
  float e = s + ldx(em, (size_t)i*DD + d, bfm) + ldx(ro, (size_t)i*64 + (d & 63), bfm);
  enh[i*DD + d] = e;
  red[d] = e * e;
  __syncthreads();
  for (int k = 128; k > 0; k >>= 1) { if (d < k) red[d] += red[d + k]; __syncthreads(); }
  float inv = 1.0f / fmaxf(sqrtf(red[0]), 1e-12f);
  nsm[i*DD + d] = e * inv;
}

// ---------------- sim GEMM (32 rows x 1024 cols per block) + reg top-5 ----------------
// grid: (NA/1024 = 4, NA/32 = 128), 256 threads
__global__ __launch_bounds__(256) void k_sim(
    const float* __restrict__ nsm, float* __restrict__ candV, int* __restrict__ candI)
{
  __shared__ __align__(16) char smem[53760];
  float (*As)[36]  = (float(*)[36])smem;                 // [256][36]  (36864 B)
  float (*Bs)[132] = (float(*)[132])(smem + 36864);      // [32][132]  (16896 B)
  int tid = threadIdx.x;
  int chunk = blockIdx.x;
  int rb = blockIdx.y * 32;
  int cb = chunk * 1024;
  int tr = tid >> 5;   // 0..7  -> rows tr*4+i
  int tc = tid & 31;   // 0..31 -> cols tc*4+j within 128-col tile

  // stage A: 32 rows x 256 K, transposed -> As[k][row]
  {
    int r = tid >> 3;          // 0..31
    int kb = (tid & 7) * 32;   // 0,32,...,224
    const float4* src = (const float4*)&nsm[(size_t)(rb + r)*DD + kb];
    #pragma unroll
    for (int q = 0; q < 8; q++) {
      float4 v = src[q];
      As[kb + q*4 + 0][r] = v.x; As[kb + q*4 + 1][r] = v.y;
      As[kb + q*4 + 2][r] = v.z; As[kb + q*4 + 3][r] = v.w;
    }
  }

  float tv[4][5]; int ti[4][5];
  #pragma unroll
  for (int i = 0; i < 4; i++)
    #pragma unroll
    for (int k = 0; k < 5; k++) { tv[i][k] = -1e30f; ti[i][k] = 0x7fffffff; }

  for (int ct = 0; ct < 8; ct++) {
    int c0 = cb + ct * 128;
    float acc[4][4] = {{0.f,0.f,0.f,0.f},{0.f,0.f,0.f,0.f},{0.f,0.f,0.f,0.f},{0.f,0.f,0.f,0.f}};
    for (int kt = 0; kt < DD; kt += 32) {
      __syncthreads();
      { // stage B: 128 cols x 32 K -> Bs[k][col]
        int col = tid >> 1;          // 0..127
        int kq = (tid & 1) * 16;     // 0 or 16
        const float4* src = (const float4*)&nsm[(size_t)(c0 + col)*DD + kt + kq];
        #pragma unroll
        for (int q = 0; q < 4; q++) {
          float4 v = src[q];
          Bs[kq + q*4 + 0][col] = v.x; Bs[kq + q*4 + 1][col] = v.y;
          Bs[kq + q*4 + 2][col] = v.z; Bs[kq + q*4 + 3][col] = v.w;
        }
      }
      __syncthreads();
      #pragma unroll
      for (int kk = 0; kk < 32; kk++) {
        float4 av = *(float4*)&As[kt + kk][tr*4];
        float4 bv = *(float4*)&Bs[kk][tc*4];
        acc[0][0] += av.x*bv.x; acc[0][1] += av.x*bv.y; acc[0][2] += av.x*bv.z; acc[0][3] += av.x*bv.w;
        acc[1][0] += av.y*bv.x; acc[1][1] += av.y*bv.y; acc[1][2] += av.y*bv.z; acc[1][3] += av.y*bv.w;
        acc[2][0] += av.z*bv.x; acc[2][1] += av.z*bv.y; acc[2][2] += av.z*bv.z; acc[2][3] += av.z*bv.w;
        acc[3][0] += av.w*bv.x; acc[3][1] += av.w*bv.y; acc[3][2] += av.w*bv.z; acc[3][3] += av.w*bv.w;
      }
    }
    // register top-5 update (fully unrolled -> no scratch)
    #pragma unroll
    for (int i = 0; i < 4; i++) {
      #pragma unroll
      for (int j = 0; j < 4; j++) {
        float v = acc[i][j];
        int c = c0 + tc*4 + j;
        if (kbetter(v, c, tv[i][4], ti[i][4])) {
          tv[i][4] = v; ti[i][4] = c;
          #pragma unroll
          for (int p = 4; p > 0; p--) {
            if (kbetter(tv[i][p], ti[i][p], tv[i][p-1], ti[i][p-1])) {
              float tmv = tv[i][p]; tv[i][p] = tv[i][p-1]; tv[i][p-1] = tmv;
              int tmi = ti[i][p]; ti[i][p] = ti[i][p-1]; ti[i][p-1] = tmi;
            }
          }
        }
      }
    }
  }

  // intra-block merge: alias smem as cand arrays [32][160]
  __syncthreads();   // all As/Bs reads done
  float* cV = (float*)smem;             // 32*160*4 = 20480 B
  int*   cI = (int*)(smem + 20480);     // 32*160*4 = 20480 B
  #pragma unroll
  for (int i = 0; i < 4; i++) {
    int r = tr*4 + i;
    #pragma unroll
    for (int k = 0; k < 5; k++) { cV[r*160 + tc*5 + k] = tv[i][k]; cI[r*160 + tc*5 + k] = ti[i][k]; }
  }
  __syncthreads();
  if (tid < 32) {
    int r = tid;
    float bv[5]; int bi[5];
    #pragma unroll
    for (int k = 0; k < 5; k++) { bv[k] = -1e30f; bi[k] = 0x7fffffff; }
    for (int s = 0; s < 160; s++) {
      float v = cV[r*160 + s]; int c = cI[r*160 + s];
      if (kbetter(v, c, bv[4], bi[4])) {
        bv[4] = v; bi[4] = c;
        #pragma unroll
        for (int p = 4; p > 0; p--) {
          if (kbetter(bv[p], bi[p], bv[p-1], bi[p-1])) {
            float tmv = bv[p]; bv[p] = bv[p-1]; bv[p-1] = tmv;
            int tmi = bi[p]; bi[p] = bi[p-1]; bi[p-1] = tmi;
          }
        }
      }
    }
    int row = rb + r;
    #pragma unroll
    for (int k = 0; k < 5; k++) {
      candV[(size_t)row*20 + chunk*5 + k] = bv[k];
      candI[(size_t)row*20 + chunk*5 + k] = bi[k];
    }
  }
}

// ---------------- final top-5 merge + adjacency bits ----------------
__global__ __launch_bounds__(256) void k_topk(
    const float* __restrict__ candV, const int* __restrict__ candI,
    unsigned long long* __restrict__ maskbits)
{
  int row = blockIdx.x * 256 + threadIdx.x;
  float bv[5]; int bi[5];
  #pragma unroll
  for (int k = 0; k < 5; k++) { bv[k] = -1e30f; bi[k] = 0x7fffffff; }
  for (int s = 0; s < 20; s++) {
    float v = candV[(size_t)row*20 + s]; int c = candI[(size_t)row*20 + s];
    if (kbetter(v, c, bv[4], bi[4])) {
      bv[4] = v; bi[4] = c;
      #pragma unroll
      for (int p = 4; p > 0; p--) {
        if (kbetter(bv[p], bi[p], bv[p-1], bi[p-1])) {
          float tmv = bv[p]; bv[p] = bv[p-1]; bv[p-1] = tmv;
          int tmi = bi[p]; bi[p] = bi[p-1]; bi[p-1] = tmi;
        }
      }
    }
  }
  atomicOr(&maskbits[(size_t)row*64 + (row >> 6)], 1ull << (row & 63));
  #pragma unroll
  for (int k = 0; k < 5; k++) {
    int j = bi[k];
    atomicOr(&maskbits[(size_t)row*64 + (j >> 6)], 1ull << (j & 63));
    atomicOr(&maskbits[(size_t)j*64 + (row >> 6)], 1ull << (row & 63));
  }
}

// ---------------- generic fp32 x (bf16|fp32) GEMM with elem offset ----------------
__global__ __launch_bounds__(256) void k_gemm(
    const float* __restrict__ Aim, const void* __restrict__ Bw, long boff,
    const void* __restrict__ bias, const float* __restrict__ resid,
    const int* __restrict__ flag,
    float* __restrict__ Cf, void* __restrict__ Cb,
    int M, int N, int Kd, int act, int accF)
{
  __shared__ float As[16][68];
  __shared__ float Bsh[16][68];
  int bfm = flag[0];
  int tid = threadIdx.x;
  int tx = tid & 15, ty = tid >> 4;
  int n0 = blockIdx.x * 64, m0 = blockIdx.y * 64;
  float acc[4][4] = {{0.f,0.f,0.f,0.f},{0.f,0.f,0.f,0.f},{0.f,0.f,0.f,0.f},{0.f,0.f,0.f,0.f}};
  for (int k0 = 0; k0 < Kd; k0 += 16) {
    {
      int ar = tid >> 2, kq = (tid & 3) * 4;
      float4 v = *(const float4*)&Aim[(size_t)(m0 + ar)*Kd + k0 + kq];
      As[kq+0][ar] = v.x; As[kq+1][ar] = v.y; As[kq+2][ar] = v.z; As[kq+3][ar] = v.w;
    }
    {
      int br = tid >> 4, nq = (tid & 15) * 4;
      int n = n0 + nq;
      float f0 = 0.f, f1 = 0.f, f2 = 0.f, f3 = 0.f;
      if (n < N) {
        size_t idx = (size_t)boff + (size_t)(k0 + br)*N + n;
        if (bfm) {
          uint2 raw = *(const uint2*)((const bf16*)Bw + idx);
          f0 = u2f(raw.x << 16); f1 = u2f(raw.x & 0xffff0000u);
          f2 = u2f(raw.y << 16); f3 = u2f(raw.y & 0xffff0000u);
        } else {
          float4 v = *(const float4*)((const float*)Bw + idx);
          f0 = v.x; f1 = v.y; f2 = v.z; f3 = v.w;
        }
      }
      Bsh[br][nq+0] = f0; Bsh[br][nq+1] = f1; Bsh[br][nq+2] = f2; Bsh[br][nq+3] = f3;
    }
    __syncthreads();
    #pragma unroll
    for (int kk = 0; kk < 16; kk++) {
      float4 av = *(float4*)&As[kk][ty*4];
      float4 bv = *(float4*)&Bsh[kk][tx*4];
      acc[0][0] += av.x*bv.x; acc[0][1] += av.x*bv.y; acc[0][2] += av.x*bv.z; acc[0][3] += av.x*bv.w;
      acc[1][0] += av.y*bv.x; acc[1][1] += av.y*bv.y; acc[1][2] += av.y*bv.z; acc[1][3] += av.y*bv.w;
      acc[2][0] += av.z*bv.x; acc[2][1] += av.z*bv.y; acc[2][2] += av.z*bv.z; acc[2][3] += av.z*bv.w;
      acc[3][0] += av.w*bv.x; acc[3][1] += av.w*bv.y; acc[3][2] += av.w*bv.z; acc[3][3] += av.w*bv.w;
    }
    __syncthreads();
  }
  #pragma unroll
  for (int i = 0; i < 4; i++) {
    int row = m0 + ty*4 + i;
    #pragma unroll
    for (int j = 0; j < 4; j++) {
      int col = n0 + tx*4 + j;
      if (col >= N) continue;
      size_t idx = (size_t)row*N + col;
      float v = acc[i][j];
      if (accF) v += Cf[idx];
      if (bias) v += ldx(bias, col, bfm);
      if (act == 1) v = fmaxf(v, 0.0f);
      if (resid) v += resid[idx];
      if (Cb) {
        if (bfm) ((bf16*)Cb)[idx] = __float2bfloat16(v);
        else ((float*)Cb)[idx] = v;
      } else Cf[idx] = v;
    }
  }
}

// ---------------- a_s, a_d ----------------
__global__ __launch_bounds__(256) void k_asd(
    const float* __restrict__ xs, const void* __restrict__ asrc, const void* __restrict__ adst,
    long loff, const int* __restrict__ flag,
    float* __restrict__ aS, float* __restrict__ aD)
{
  int i = blockIdx.x, t = threadIdx.x;
  int bfm = flag[0];
  __shared__ float rs[256], rd[256];
  float xv = xs[(size_t)i*DD + t];
  rs[t] = xv * ldx(asrc, loff + t, bfm);
  rd[t] = xv * ldx(adst, loff + t, bfm);
  __syncthreads();
  for (int k = 32; k > 0; k >>= 1) {
    if ((t & 63) < k) { rs[t] += rs[t + k]; rd[t] += rd[t + k]; }
    __syncthreads();
  }
  if ((t & 63) == 0) { int h = t >> 6; aS[i*HH + h] = rs[t]; aD[i*HH + h] = rd[t]; }
}

// ---------------- GAT aggregation + bias + LN + residual ----------------
__global__ __launch_bounds__(256) void k_gatagg(
    const float* __restrict__ xs, const float* __restrict__ aS, const float* __restrict__ aD,
    const unsigned long long* __restrict__ maskbits,
    const void* __restrict__ gbias, const void* __restrict__ lng, const void* __restrict__ lnb,
    long loff, const int* __restrict__ flag,
    const float* __restrict__ xold, float* __restrict__ xnew)
{
  __shared__ int nbr[NA];
  __shared__ float alph[NA];
  __shared__ float red[256];
  __shared__ float outv[DD];
  __shared__ int offs[64];
  __shared__ int degS;
  int j = blockIdx.x, t = threadIdx.x;
  int bfm = flag[0];
  unsigned long long bits = 0;
  if (t < 64) { bits = maskbits[(size_t)j*64 + t]; offs[t] = __popcll(bits); }
  __syncthreads();
  if (t == 0) { int run = 0; for (int w = 0; w < 64; w++) { int c = offs[w]; offs[w] = run; run += c; } degS = run; }
  __syncthreads();
  if (t < 64) {
    int base = offs[t];
    unsigned long long b = bits;
    while (b) { int p = __builtin_ctzll(b); nbr[base++] = t*64 + p; b &= b - 1; }
  }
  __syncthreads();
  int deg = degS;
  for (int h = 0; h < HH; h++) {
    float adjv = aD[j*HH + h];
    float lm = -1e30f;
    for (int n = t; n < deg; n += 256) {
      float lg = aS[nbr[n]*HH + h] + adjv;
      lg = (lg >= 0.f) ? lg : 0.2f*lg;
      alph[n] = lg;
      lm = fmaxf(lm, lg);
    }
    red[t] = lm; __syncthreads();
    for (int k = 128; k > 0; k >>= 1) { if (t < k) red[t] = fmaxf(red[t], red[t + k]); __syncthreads(); }
    float Mx = red[0];
    __syncthreads();
    float ls = 0.f;
    for (int n = t; n < deg; n += 256) { float w = __expf(alph[n] - Mx); alph[n] = w; ls += w; }
    red[t] = ls; __syncthreads();
    for (int k = 128; k > 0; k >>= 1) { if (t < k) red[t] += red[t + k]; __syncthreads(); }
    float Z = red[0];
    __syncthreads();
    int c = t & 63, q = t >> 6;
    float a2 = 0.f;
    for (int n = q; n < deg; n += 4) a2 += alph[n] * xs[(size_t)nbr[n]*DD + h*CC + c];
    red[t] = a2; __syncthreads();
    if (q == 0) outv[h*CC + c] = (red[c] + red[c+64] + red[c+128] + red[c+192]) / Z;
    __syncthreads();
  }
  float v = outv[t] + ldx(gbias, loff + t, bfm);
  red[t] = v; __syncthreads();
  for (int k = 128; k > 0; k >>= 1) { if (t < k) red[t] += red[t + k]; __syncthreads(); }
  float mu = red[0] * (1.0f/DD);
  __syncthreads();
  float dv = v - mu;
  red[t] = dv*dv; __syncthreads();
  for (int k = 128; k > 0; k >>= 1) { if (t < k) red[t] += red[t + k]; __syncthreads(); }
  float var = red[0] * (1.0f/DD);
  float xn = ldx(lng, loff + t, bfm) * dv * rsqrtf(var + 1e-5f) + ldx(lnb, loff + t, bfm) + xold[(size_t)j*DD + t];
  xnew[(size_t)j*DD + t] = xn;
}

// ---------------- flash-style MHA ----------------
__global__ __launch_bounds__(128) void k_mha(const float* __restrict__ qkv, float* __restrict__ ctx)
{
  __shared__ float QsT[64][36];
  __shared__ float KsT[64][68];
  __shared__ float Vs[64][68];
  __shared__ float SsT[64][36];
  int tid = threadIdx.x;
  int h = blockIdx.y;
  int q0 = blockIdx.x * 32;
  int tr = tid >> 4, tc = tid & 15;
  {
    int r = tid >> 2, c16 = (tid & 3) * 16;
    const float* qp = &qkv[(size_t)(q0 + r)*768 + h*64 + c16];
    #pragma unroll
    for (int q = 0; q < 4; q++) {
      float4 v = *(const float4*)(qp + q*4);
      QsT[c16 + q*4 + 0][r] = v.x; QsT[c16 + q*4 + 1][r] = v.y;
      QsT[c16 + q*4 + 2][r] = v.z; QsT[c16 + q*4 + 3][r] = v.w;
    }
  }
  float m[4] = {-1e30f,-1e30f,-1e30f,-1e30f};
  float l[4] = {0.f,0.f,0.f,0.f};
  float acc[4][4] = {{0.f,0.f,0.f,0.f},{0.f,0.f,0.f,0.f},{0.f,0.f,0.f,0.f},{0.f,0.f,0.f,0.f}};
  for (int kt = 0; kt < NA; kt += 64) {
    __syncthreads();
    {
      int rr = tid >> 1, c32 = (tid & 1) * 32;
      const float* kp = &qkv[(size_t)(kt + rr)*768 + 256 + h*64 + c32];
      const float* vp = kp + 256;
      #pragma unroll
      for (int q = 0; q < 8; q++) {
        float4 kv = *(const float4*)(kp + q*4);
        KsT[c32 + q*4 + 0][rr] = kv.x; KsT[c32 + q*4 + 1][rr] = kv.y;
        KsT[c32 + q*4 + 2][rr] = kv.z; KsT[c32 + q*4 + 3][rr] = kv.w;
        *(float4*)&Vs[rr][c32 + q*4] = *(const float4*)(vp + q*4);
      }
    }
    __syncthreads();
    float s[4][4] = {{0.f,0.f,0.f,0.f},{0.f,0.f,0.f,0.f},{0.f,0.f,0.f,0.f},{0.f,0.f,0.f,0.f}};
    #pragma unroll 8
    for (int d = 0; d < 64; d++) {
      float4 av = *(float4*)&QsT[d][tr*4];
      float4 bv = *(float4*)&KsT[d][tc*4];
      s[0][0] += av.x*bv.x; s[0][1] += av.x*bv.y; s[0][2] += av.x*bv.z; s[0][3] += av.x*bv.w;
      s[1][0] += av.y*bv.x; s[1][1] += av.y*bv.y; s[1][2] += av.y*bv.z; s[1][3] += av.y*bv.w;
      s[2][0] += av.z*bv.x; s[2][1] += av.z*bv.y; s[2][2] += av.z*bv.z; s[2][3] += av.z*bv.w;
      s[3][0] += av.w*bv.x; s[3][1] += av.w*bv.y; s[3][2] += av.w*bv.z; s[3][3] += av.w*bv.w;
    }
    #pragma unroll
    for (int i = 0; i < 4; i++) {
      #pragma unroll
      for (int q = 0; q < 4; q++) s[i][q] *= 0.125f;
      float rm = fmaxf(fmaxf(s[i][0], s[i][1]), fmaxf(s[i][2], s[i][3]));
      #pragma unroll
      for (int off = 1; off < 16; off <<= 1) rm = fmaxf(rm, __shfl_xor(rm, off, 16));
      float mn = fmaxf(m[i], rm);
      float corr = __expf(m[i] - mn);
      float p0 = __expf(s[i][0] - mn), p1 = __expf(s[i][1] - mn);
      float p2 = __expf(s[i][2] - mn), p3 = __expf(s[i][3] - mn);
      float ps = p0 + p1 + p2 + p3;
      #pragma unroll
      for (int off = 1; off < 16; off <<= 1) ps += __shfl_xor(ps, off, 16);
      m[i] = mn;
      l[i] = l[i]*corr + ps;
      acc[i][0] *= corr; acc[i][1] *= corr; acc[i][2] *= corr; acc[i][3] *= corr;
      SsT[tc*4 + 0][tr*4 + i] = p0; SsT[tc*4 + 1][tr*4 + i] = p1;
      SsT[tc*4 + 2][tr*4 + i] = p2; SsT[tc*4 + 3][tr*4 + i] = p3;
    }
    __syncthreads();
    #pragma unroll 4
    for (int jj = 0; jj < 64; jj++) {
      float4 pv = *(float4*)&SsT[jj][tr*4];
      float4 vv = *(float4*)&Vs[jj][tc*4];
      acc[0][0] += pv.x*vv.x; acc[0][1] += pv.x*vv.y; acc[0][2] += pv.x*vv.z; acc[0][3] += pv.x*vv.w;
      acc[1][0] += pv.y*vv.x; acc[1][1] += pv.y*vv.y; acc[1][2] += pv.y*vv.z; acc[1][3] += pv.y*vv.w;
      acc[2][0] += pv.z*vv.x; acc[2][1] += pv.z*vv.y; acc[2][2] += pv.z*vv.z; acc[2][3] += pv.z*vv.w;
      acc[3][0] += pv.w*vv.x; acc[3][1] += pv.w*vv.y; acc[3][2] += pv.w*vv.z; acc[3][3] += pv.w*vv.w;
    }
  }
  #pragma unroll
  for (int i = 0; i < 4; i++) {
    float inv = 1.0f / l[i];
    float4 o; o.x = acc[i][0]*inv; o.y = acc[i][1]*inv; o.z = acc[i][2]*inv; o.w = acc[i][3]*inv;
    *(float4*)&ctx[(size_t)(q0 + tr*4 + i)*DD + h*CC + tc*4] = o;
  }
}

// ---------------- gate ----------------
__global__ __launch_bounds__(256) void k_gate(
    const float* __restrict__ g1, const void* __restrict__ w2, const void* __restrict__ b2v,
    const int* __restrict__ flag,
    const float* __restrict__ agg, float* __restrict__ ag2)
{
  int i = blockIdx.x, t = threadIdx.x;
  int bfm = flag[0];
  __shared__ float red[256];
  red[t] = g1[(size_t)i*DD + t] * ldx(w2, t, bfm);
  __syncthreads();
  for (int k = 128; k > 0; k >>= 1) { if (t < k) red[t] += red[t + k]; __syncthreads(); }
  float sr = red[0] + ldx(b2v, 0, bfm);
  float s = 1.0f / (1.0f + __expf(-sr));
  ag2[(size_t)i*DD + t] = agg[(size_t)i*DD + t] * s;
}

extern "C" void kernel_launch(void* const* d_in, const int* in_sizes, int n_in,
                              void* d_out, int out_size, void* d_ws, size_t ws_size,
                              hipStream_t stream) {
  (void)in_sizes; (void)n_in; (void)out_size; (void)ws_size;
  const void* agent_states = d_in[0];
  const void* agent_emb    = d_in[1];
  const void* role_emb     = d_in[2];
  const void* gat_W        = d_in[3];
  const void* gat_att_src  = d_in[4];
  const void* gat_att_dst  = d_in[5];
  const void* gat_bias     = d_in[6];
  const void* ln_gamma     = d_in[7];
  const void* ln_beta      = d_in[8];
  const void* enc_W1 = d_in[9];
  const void* enc_b1 = d_in[10];
  const void* enc_W2 = d_in[11];
  const void* enc_b2 = d_in[12];
  const void* dec_W1 = d_in[13];
  const void* dec_b1 = d_in[14];
  const void* dec_W2 = d_in[15];
  const void* dec_b2 = d_in[16];
  const void* mha_in_w  = d_in[17];
  const void* mha_in_b  = d_in[18];
  const void* mha_out_w = d_in[19];
  const void* mha_out_b = d_in[20];
  const void* proj_W = d_in[21];
  const void* proj_b = d_in[22];
  const void* gate_W1 = d_in[23];
  const void* gate_b1 = d_in[24];
  const void* gate_W2 = d_in[25];
  const void* gate_b2 = d_in[26];

  char* base = (char*)d_ws;
  size_t off = 0;
  auto alloc = [&](size_t nbytes) -> char* {
    char* p = base + off; off += (nbytes + 255) & ~(size_t)255; return p;
  };
  int* flag = (int*)alloc(256);
  float* statesF = (float*)alloc((size_t)NA*DD*4);
  float* enh     = (float*)alloc((size_t)NA*DD*4);
  float* nsb     = (float*)alloc((size_t)NA*DD*4);
  unsigned long long* maskbits = (unsigned long long*)alloc((size_t)NA*64*8);
  float* xs  = (float*)alloc((size_t)NA*DD*4);
  float* xB  = (float*)alloc((size_t)NA*DD*4);
  float* qkv = (float*)alloc((size_t)NA*3*DD*4);
  float* dec = (float*)alloc((size_t)NA*DD*4);
  float* agg = (float*)alloc((size_t)NA*DD*4);
  float* candV = (float*)alloc((size_t)NA*20*4);
  int*   candI = (int*)alloc((size_t)NA*20*4);
  float* xC  = enh;
  float* aS  = nsb;
  float* aD  = nsb + NA*HH;
  float* h1  = nsb + 2*NA*HH;
  float* msg = h1 + (size_t)NA*64;
  float* dh  = msg + (size_t)NA*32;
  float* ctx = dec;
  float* g1  = xs;
  float* ag2 = xB;

  auto gemm = [&](const float* A, const void* B, long boff, const void* bias, const float* resid,
                  float* Cf, void* Cb, int M, int Nn, int Kd, int act, int accF) {
    dim3 g((Nn + 63)/64, M/64);
    hipLaunchKernelGGL(k_gemm, g, dim3(256), 0, stream, A, B, boff, bias, resid, flag, Cf, Cb, M, Nn, Kd, act, accF);
  };

  hipMemsetAsync(maskbits, 0, (size_t)NA*64*8, stream);
  hipLaunchKernelGGL(k_detect, dim3(1), dim3(256), 0, stream, agent_states, flag);
  hipLaunchKernelGGL(k_prep, dim3(NA), dim3(256), 0, stream,
                     agent_states, agent_emb, role_emb, flag, statesF, enh, nsb);
  hipLaunchKernelGGL(k_sim, dim3(NA/1024, NA/32), dim3(256), 0, stream, nsb, candV, candI);
  hipLaunchKernelGGL(k_topk, dim3(NA/256), dim3(256), 0, stream, candV, candI, maskbits);

  const float* xin = enh;
  float* xout = xB;
  for (int l = 0; l < LL; l++) {
    gemm(xin, gat_W, (long)l*DD*DD, nullptr, nullptr, xs, nullptr, NA, DD, DD, 0, 0);
    hipLaunchKernelGGL(k_asd, dim3(NA), dim3(256), 0, stream,
                       xs, gat_att_src, gat_att_dst, (long)l*DD, flag, aS, aD);
    hipLaunchKernelGGL(k_gatagg, dim3(NA), dim3(256), 0, stream,
                       xs, aS, aD, maskbits, gat_bias, ln_gamma, ln_beta, (long)l*DD, flag, xin, xout);
    xin = xout; xout = xC;
  }
  gemm(xin, enc_W1, 0, enc_b1, nullptr, h1, nullptr, NA, 64, DD, 1, 0);
  gemm(h1, enc_W2, 0, enc_b2, nullptr, msg, nullptr, NA, 32, 64, 0, 0);
  gemm(msg, dec_W1, 0, dec_b1, nullptr, dh, nullptr, NA, 128, 32, 1, 0);
  gemm(dh, dec_W2, 0, dec_b2, nullptr, dec, nullptr, NA, DD, 128, 0, 0);
  gemm(dec, mha_in_w, 0, mha_in_b, nullptr, qkv, nullptr, NA, 3*DD, DD, 0, 0);
  hipLaunchKernelGGL(k_mha, dim3(NA/32, HH), dim3(128), 0, stream, qkv, ctx);
  gemm(ctx, mha_out_w, 0, mha_out_b, nullptr, agg, nullptr, NA, DD, DD, 0, 0);
  gemm(statesF, gate_W1, 0, nullptr, nullptr, g1, nullptr, NA, DD, DD, 0, 0);
  gemm(agg, gate_W1, (long)DD*DD, gate_b1, nullptr, g1, nullptr, NA, DD, DD, 1, 1);
  hipLaunchKernelGGL(k_gate, dim3(NA), dim3(256), 0, stream, g1, gate_W2, gate_b2, flag, agg, ag2);
  gemm(ag2, proj_W, 0, proj_b, statesF, nullptr, d_out, NA, DD, DD, 0, 0);
}

// Round 4
// 673.201 us; speedup vs baseline: 2.3882x; 1.5825x over previous
//
#include <hip/hip_runtime.h>
#include <hip/hip_bf16.h>

#define NA 4096
#define DD 256
#define HH 4
#define CC 64
#define LL 2
#define TOPK 5

typedef __hip_bfloat16 bf16;
typedef __attribute__((ext_vector_type(8))) short bf16x8;
typedef __attribute__((ext_vector_type(4))) float f32x4;

__device__ __forceinline__ float b2f(bf16 v) { return __bfloat162float(v); }
__device__ __forceinline__ float u2f(unsigned int u) { union { unsigned int i; float f; } x; x.i = u; return x.f; }
__device__ __forceinline__ unsigned short f2bf(float f) {
  bf16 b = __float2bfloat16(f);
  return *reinterpret_cast<unsigned short*>(&b);
}
__device__ __forceinline__ float ldx(const void* p, size_t i, int bfm) {
  return bfm ? b2f(((const bf16*)p)[i]) : ((const float*)p)[i];
}
__device__ __forceinline__ bool kbetter(float v, int c, float v2, int c2) {
  return (v > v2) || (v == v2 && c < c2);
}

// ---------------- dtype detect: bf16 vs fp32 ----------------
__global__ __launch_bounds__(256) void k_detect(const void* probe, int* flag) {
  __shared__ int cnt;
  if (threadIdx.x == 0) cnt = 0;
  __syncthreads();
  const unsigned short* u = (const unsigned short*)probe;
  int bad = 0;
  for (int i = threadIdx.x; i < 2048; i += 256) {
    float v = u2f(((unsigned int)u[i]) << 16);
    if (!(fabsf(v) <= 1e10f)) bad++;
  }
  atomicAdd(&cnt, bad);
  __syncthreads();
  if (threadIdx.x == 0) flag[0] = (cnt < 64) ? 1 : 0;
}

// ---------------- prep ----------------
__global__ __launch_bounds__(256) void k_prep(
    const void* __restrict__ st, const void* __restrict__ em, const void* __restrict__ ro,
    const int* __restrict__ flag,
    float* __restrict__ statesF, float* __restrict__ enh, float* __restrict__ nsm)
{
  int i = blockIdx.x, d = threadIdx.x;
  int bfm = flag[0];
  __shared__ float red[256];
  float s = ldx(st, (size_t)i*DD + d, bfm);
  statesF[i*DD + d] = s;
  float e = s + ldx(em, (size_t)i*DD + d, bfm) + ldx(ro, (size_t)i*64 + (d & 63), bfm);
  enh[i*DD + d] = e;
  red[d] = e * e;
  __syncthreads();
  for (int k = 128; k > 0; k >>= 1) { if (d < k) red[d] += red[d + k]; __syncthreads(); }
  float inv = 1.0f / fmaxf(sqrtf(red[0]), 1e-12f);
  nsm[i*DD + d] = e * inv;
}

// ---------------- sim GEMM (32 rows x 1024 cols per block) + reg top-5 ----------------
__global__ __launch_bounds__(256) void k_sim(
    const float* __restrict__ nsm, float* __restrict__ candV, int* __restrict__ candI)
{
  __shared__ __align__(16) char smem[53760];
  float (*As)[36]  = (float(*)[36])smem;
  float (*Bs)[132] = (float(*)[132])(smem + 36864);
  int tid = threadIdx.x;
  int chunk = blockIdx.x;
  int rb = blockIdx.y * 32;
  int cb = chunk * 1024;
  int tr = tid >> 5, tc = tid & 31;
  {
    int r = tid >> 3;
    int kb = (tid & 7) * 32;
    const float4* src = (const float4*)&nsm[(size_t)(rb + r)*DD + kb];
    #pragma unroll
    for (int q = 0; q < 8; q++) {
      float4 v = src[q];
      As[kb + q*4 + 0][r] = v.x; As[kb + q*4 + 1][r] = v.y;
      As[kb + q*4 + 2][r] = v.z; As[kb + q*4 + 3][r] = v.w;
    }
  }
  float tv[4][5]; int ti[4][5];
  #pragma unroll
  for (int i = 0; i < 4; i++)
    #pragma unroll
    for (int k = 0; k < 5; k++) { tv[i][k] = -1e30f; ti[i][k] = 0x7fffffff; }

  for (int ct = 0; ct < 8; ct++) {
    int c0 = cb + ct * 128;
    float acc[4][4] = {{0.f,0.f,0.f,0.f},{0.f,0.f,0.f,0.f},{0.f,0.f,0.f,0.f},{0.f,0.f,0.f,0.f}};
    for (int kt = 0; kt < DD; kt += 32) {
      __syncthreads();
      {
        int col = tid >> 1;
        int kq = (tid & 1) * 16;
        const float4* src = (const float4*)&nsm[(size_t)(c0 + col)*DD + kt + kq];
        #pragma unroll
        for (int q = 0; q < 4; q++) {
          float4 v = src[q];
          Bs[kq + q*4 + 0][col] = v.x; Bs[kq + q*4 + 1][col] = v.y;
          Bs[kq + q*4 + 2][col] = v.z; Bs[kq + q*4 + 3][col] = v.w;
        }
      }
      __syncthreads();
      #pragma unroll
      for (int kk = 0; kk < 32; kk++) {
        float4 av = *(float4*)&As[kt + kk][tr*4];
        float4 bv = *(float4*)&Bs[kk][tc*4];
        acc[0][0] += av.x*bv.x; acc[0][1] += av.x*bv.y; acc[0][2] += av.x*bv.z; acc[0][3] += av.x*bv.w;
        acc[1][0] += av.y*bv.x; acc[1][1] += av.y*bv.y; acc[1][2] += av.y*bv.z; acc[1][3] += av.y*bv.w;
        acc[2][0] += av.z*bv.x; acc[2][1] += av.z*bv.y; acc[2][2] += av.z*bv.z; acc[2][3] += av.z*bv.w;
        acc[3][0] += av.w*bv.x; acc[3][1] += av.w*bv.y; acc[3][2] += av.w*bv.z; acc[3][3] += av.w*bv.w;
      }
    }
    #pragma unroll
    for (int i = 0; i < 4; i++) {
      #pragma unroll
      for (int j = 0; j < 4; j++) {
        float v = acc[i][j];
        int c = c0 + tc*4 + j;
        if (kbetter(v, c, tv[i][4], ti[i][4])) {
          tv[i][4] = v; ti[i][4] = c;
          #pragma unroll
          for (int p = 4; p > 0; p--) {
            if (kbetter(tv[i][p], ti[i][p], tv[i][p-1], ti[i][p-1])) {
              float tmv = tv[i][p]; tv[i][p] = tv[i][p-1]; tv[i][p-1] = tmv;
              int tmi = ti[i][p]; ti[i][p] = ti[i][p-1]; ti[i][p-1] = tmi;
            }
          }
        }
      }
    }
  }
  __syncthreads();
  float* cV = (float*)smem;
  int*   cI = (int*)(smem + 20480);
  #pragma unroll
  for (int i = 0; i < 4; i++) {
    int r = tr*4 + i;
    #pragma unroll
    for (int k = 0; k < 5; k++) { cV[r*160 + tc*5 + k] = tv[i][k]; cI[r*160 + tc*5 + k] = ti[i][k]; }
  }
  __syncthreads();
  if (tid < 32) {
    int r = tid;
    float bv[5]; int bi[5];
    #pragma unroll
    for (int k = 0; k < 5; k++) { bv[k] = -1e30f; bi[k] = 0x7fffffff; }
    for (int s = 0; s < 160; s++) {
      float v = cV[r*160 + s]; int c = cI[r*160 + s];
      if (kbetter(v, c, bv[4], bi[4])) {
        bv[4] = v; bi[4] = c;
        #pragma unroll
        for (int p = 4; p > 0; p--) {
          if (kbetter(bv[p], bi[p], bv[p-1], bi[p-1])) {
            float tmv = bv[p]; bv[p] = bv[p-1]; bv[p-1] = tmv;
            int tmi = bi[p]; bi[p] = bi[p-1]; bi[p-1] = tmi;
          }
        }
      }
    }
    int row = rb + r;
    #pragma unroll
    for (int k = 0; k < 5; k++) {
      candV[(size_t)row*20 + chunk*5 + k] = bv[k];
      candI[(size_t)row*20 + chunk*5 + k] = bi[k];
    }
  }
}

// ---------------- final top-5 merge + adjacency bits ----------------
__global__ __launch_bounds__(256) void k_topk(
    const float* __restrict__ candV, const int* __restrict__ candI,
    unsigned long long* __restrict__ maskbits)
{
  int row = blockIdx.x * 256 + threadIdx.x;
  float bv[5]; int bi[5];
  #pragma unroll
  for (int k = 0; k < 5; k++) { bv[k] = -1e30f; bi[k] = 0x7fffffff; }
  for (int s = 0; s < 20; s++) {
    float v = candV[(size_t)row*20 + s]; int c = candI[(size_t)row*20 + s];
    if (kbetter(v, c, bv[4], bi[4])) {
      bv[4] = v; bi[4] = c;
      #pragma unroll
      for (int p = 4; p > 0; p--) {
        if (kbetter(bv[p], bi[p], bv[p-1], bi[p-1])) {
          float tmv = bv[p]; bv[p] = bv[p-1]; bv[p-1] = tmv;
          int tmi = bi[p]; bi[p] = bi[p-1]; bi[p-1] = tmi;
        }
      }
    }
  }
  atomicOr(&maskbits[(size_t)row*64 + (row >> 6)], 1ull << (row & 63));
  #pragma unroll
  for (int k = 0; k < 5; k++) {
    int j = bi[k];
    atomicOr(&maskbits[(size_t)row*64 + (j >> 6)], 1ull << (j & 63));
    atomicOr(&maskbits[(size_t)j*64 + (row >> 6)], 1ull << (row & 63));
  }
}

// ---------------- generic fp32 x (bf16|fp32) GEMM; smode: 0=f32 Cf, 1=bf16 Cb, 2=per-bfm Cb ----------------
__global__ __launch_bounds__(256) void k_gemm(
    const float* __restrict__ Aim, const void* __restrict__ Bw, long boff,
    const void* __restrict__ bias, const float* __restrict__ resid,
    const int* __restrict__ flag,
    float* __restrict__ Cf, void* __restrict__ Cb,
    int M, int N, int Kd, int act, int accF, int smode)
{
  __shared__ float As[16][68];
  __shared__ float Bsh[16][68];
  int bfm = flag[0];
  int tid = threadIdx.x;
  int tx = tid & 15, ty = tid >> 4;
  int n0 = blockIdx.x * 64, m0 = blockIdx.y * 64;
  float acc[4][4] = {{0.f,0.f,0.f,0.f},{0.f,0.f,0.f,0.f},{0.f,0.f,0.f,0.f},{0.f,0.f,0.f,0.f}};
  for (int k0 = 0; k0 < Kd; k0 += 16) {
    {
      int ar = tid >> 2, kq = (tid & 3) * 4;
      float4 v = *(const float4*)&Aim[(size_t)(m0 + ar)*Kd + k0 + kq];
      As[kq+0][ar] = v.x; As[kq+1][ar] = v.y; As[kq+2][ar] = v.z; As[kq+3][ar] = v.w;
    }
    {
      int br = tid >> 4, nq = (tid & 15) * 4;
      int n = n0 + nq;
      float f0 = 0.f, f1 = 0.f, f2 = 0.f, f3 = 0.f;
      if (n < N) {
        size_t idx = (size_t)boff + (size_t)(k0 + br)*N + n;
        if (bfm) {
          uint2 raw = *(const uint2*)((const bf16*)Bw + idx);
          f0 = u2f(raw.x << 16); f1 = u2f(raw.x & 0xffff0000u);
          f2 = u2f(raw.y << 16); f3 = u2f(raw.y & 0xffff0000u);
        } else {
          float4 v = *(const float4*)((const float*)Bw + idx);
          f0 = v.x; f1 = v.y; f2 = v.z; f3 = v.w;
        }
      }
      Bsh[br][nq+0] = f0; Bsh[br][nq+1] = f1; Bsh[br][nq+2] = f2; Bsh[br][nq+3] = f3;
    }
    __syncthreads();
    #pragma unroll
    for (int kk = 0; kk < 16; kk++) {
      float4 av = *(float4*)&As[kk][ty*4];
      float4 bv = *(float4*)&Bsh[kk][tx*4];
      acc[0][0] += av.x*bv.x; acc[0][1] += av.x*bv.y; acc[0][2] += av.x*bv.z; acc[0][3] += av.x*bv.w;
      acc[1][0] += av.y*bv.x; acc[1][1] += av.y*bv.y; acc[1][2] += av.y*bv.z; acc[1][3] += av.y*bv.w;
      acc[2][0] += av.z*bv.x; acc[2][1] += av.z*bv.y; acc[2][2] += av.z*bv.z; acc[2][3] += av.z*bv.w;
      acc[3][0] += av.w*bv.x; acc[3][1] += av.w*bv.y; acc[3][2] += av.w*bv.z; acc[3][3] += av.w*bv.w;
    }
    __syncthreads();
  }
  #pragma unroll
  for (int i = 0; i < 4; i++) {
    int row = m0 + ty*4 + i;
    #pragma unroll
    for (int j = 0; j < 4; j++) {
      int col = n0 + tx*4 + j;
      if (col >= N) continue;
      size_t idx = (size_t)row*N + col;
      float v = acc[i][j];
      if (accF) v += Cf[idx];
      if (bias) v += ldx(bias, col, bfm);
      if (act == 1) v = fmaxf(v, 0.0f);
      if (resid) v += resid[idx];
      if (smode == 0) Cf[idx] = v;
      else if (smode == 1) ((bf16*)Cb)[idx] = __float2bfloat16(v);
      else {
        if (bfm) ((bf16*)Cb)[idx] = __float2bfloat16(v);
        else ((float*)Cb)[idx] = v;
      }
    }
  }
}

// ---------------- a_s, a_d ----------------
__global__ __launch_bounds__(256) void k_asd(
    const float* __restrict__ xs, const void* __restrict__ asrc, const void* __restrict__ adst,
    long loff, const int* __restrict__ flag,
    float* __restrict__ aS, float* __restrict__ aD)
{
  int i = blockIdx.x, t = threadIdx.x;
  int bfm = flag[0];
  __shared__ float rs[256], rd[256];
  float xv = xs[(size_t)i*DD + t];
  rs[t] = xv * ldx(asrc, loff + t, bfm);
  rd[t] = xv * ldx(adst, loff + t, bfm);
  __syncthreads();
  for (int k = 32; k > 0; k >>= 1) {
    if ((t & 63) < k) { rs[t] += rs[t + k]; rd[t] += rd[t + k]; }
    __syncthreads();
  }
  if ((t & 63) == 0) { int h = t >> 6; aS[i*HH + h] = rs[t]; aD[i*HH + h] = rd[t]; }
}

// ---------------- GAT aggregation + bias + LN + residual ----------------
__global__ __launch_bounds__(256) void k_gatagg(
    const float* __restrict__ xs, const float* __restrict__ aS, const float* __restrict__ aD,
    const unsigned long long* __restrict__ maskbits,
    const void* __restrict__ gbias, const void* __restrict__ lng, const void* __restrict__ lnb,
    long loff, const int* __restrict__ flag,
    const float* __restrict__ xold, float* __restrict__ xnew)
{
  __shared__ int nbr[NA];
  __shared__ float alph[NA];
  __shared__ float red[256];
  __shared__ float outv[DD];
  __shared__ int offs[64];
  __shared__ int degS;
  int j = blockIdx.x, t = threadIdx.x;
  int bfm = flag[0];
  unsigned long long bits = 0;
  if (t < 64) { bits = maskbits[(size_t)j*64 + t]; offs[t] = __popcll(bits); }
  __syncthreads();
  if (t == 0) { int run = 0; for (int w = 0; w < 64; w++) { int c = offs[w]; offs[w] = run; run += c; } degS = run; }
  __syncthreads();
  if (t < 64) {
    int base = offs[t];
    unsigned long long b = bits;
    while (b) { int p = __builtin_ctzll(b); nbr[base++] = t*64 + p; b &= b - 1; }
  }
  __syncthreads();
  int deg = degS;
  for (int h = 0; h < HH; h++) {
    float adjv = aD[j*HH + h];
    float lm = -1e30f;
    for (int n = t; n < deg; n += 256) {
      float lg = aS[nbr[n]*HH + h] + adjv;
      lg = (lg >= 0.f) ? lg : 0.2f*lg;
      alph[n] = lg;
      lm = fmaxf(lm, lg);
    }
    red[t] = lm; __syncthreads();
    for (int k = 128; k > 0; k >>= 1) { if (t < k) red[t] = fmaxf(red[t], red[t + k]); __syncthreads(); }
    float Mx = red[0];
    __syncthreads();
    float ls = 0.f;
    for (int n = t; n < deg; n += 256) { float w = __expf(alph[n] - Mx); alph[n] = w; ls += w; }
    red[t] = ls; __syncthreads();
    for (int k = 128; k > 0; k >>= 1) { if (t < k) red[t] += red[t + k]; __syncthreads(); }
    float Z = red[0];
    __syncthreads();
    int c = t & 63, q = t >> 6;
    float a2 = 0.f;
    for (int n = q; n < deg; n += 4) a2 += alph[n] * xs[(size_t)nbr[n]*DD + h*CC + c];
    red[t] = a2; __syncthreads();
    if (q == 0) outv[h*CC + c] = (red[c] + red[c+64] + red[c+128] + red[c+192]) / Z;
    __syncthreads();
  }
  float v = outv[t] + ldx(gbias, loff + t, bfm);
  red[t] = v; __syncthreads();
  for (int k = 128; k > 0; k >>= 1) { if (t < k) red[t] += red[t + k]; __syncthreads(); }
  float mu = red[0] * (1.0f/DD);
  __syncthreads();
  float dv = v - mu;
  red[t] = dv*dv; __syncthreads();
  for (int k = 128; k > 0; k >>= 1) { if (t < k) red[t] += red[t + k]; __syncthreads(); }
  float var = red[0] * (1.0f/DD);
  float xn = ldx(lng, loff + t, bfm) * dv * rsqrtf(var + 1e-5f) + ldx(lnb, loff + t, bfm) + xold[(size_t)j*DD + t];
  xnew[(size_t)j*DD + t] = xn;
}

// ---------------- MFMA flash-MHA: qkv bf16 [N][768], 4 waves x 16 q-rows, KV tile 64 ----------------
__global__ __launch_bounds__(256) void k_mha2(const bf16* __restrict__ qkvb, float* __restrict__ ctx)
{
  __shared__ unsigned short Ks[64][72];
  __shared__ unsigned short Vts[64][72];
  __shared__ unsigned short Ps[4][16][72];
  int tid = threadIdx.x;
  int lane = tid & 63;
  int w = tid >> 6;
  int h = blockIdx.y;
  int q0 = blockIdx.x * 64;
  int lr = lane & 15;
  int lg = lane >> 4;

  const unsigned short* qkvu = (const unsigned short*)qkvb;

  // Q frags: lane -> row (w*16+lr), k = kb*32 + lg*8 + j
  bf16x8 qf0, qf1;
  {
    const unsigned short* qp = qkvu + (size_t)(q0 + w*16 + lr)*768 + h*64;
    qf0 = *(const bf16x8*)(qp + lg*8);
    qf1 = *(const bf16x8*)(qp + 32 + lg*8);
  }

  // staging map: row sr = tid&63, col-seg sc = (tid>>6)*16
  int sr = tid & 63;
  int sc = (tid >> 6) * 16;
  const unsigned short* kbase = qkvu + 256 + h*64;
  const unsigned short* vbase = qkvu + 512 + h*64;

  f32x4 oacc[4];
  #pragma unroll
  for (int c = 0; c < 4; c++) oacc[c] = (f32x4){0.f,0.f,0.f,0.f};
  float mrun[4], lrun[4];
  #pragma unroll
  for (int r = 0; r < 4; r++) { mrun[r] = -1e30f; lrun[r] = 0.f; }

  // prefetch tile 0
  bf16x8 kpa, kpb, vpa, vpb;
  {
    const unsigned short* kp = kbase + (size_t)sr*768 + sc;
    kpa = *(const bf16x8*)kp; kpb = *(const bf16x8*)(kp + 8);
    const unsigned short* vp = vbase + (size_t)sr*768 + sc;
    vpa = *(const bf16x8*)vp; vpb = *(const bf16x8*)(vp + 8);
  }

  for (int kt = 0; kt < NA; kt += 64) {
    __syncthreads();   // previous tile's LDS reads done
    *(bf16x8*)&Ks[sr][sc] = kpa;
    *(bf16x8*)&Ks[sr][sc+8] = kpb;
    {
      // transpose V: loaded V[sr][sc+q] -> Vts[sc+q][sr]
      #pragma unroll
      for (int q = 0; q < 8; q++) Vts[sc + q][sr] = (unsigned short)vpa[q];
      #pragma unroll
      for (int q = 0; q < 8; q++) Vts[sc + 8 + q][sr] = (unsigned short)vpb[q];
    }
    __syncthreads();
    if (kt + 64 < NA) {  // prefetch next tile into regs (hides under compute)
      const unsigned short* kp = kbase + (size_t)(kt + 64 + sr)*768 + sc;
      kpa = *(const bf16x8*)kp; kpb = *(const bf16x8*)(kp + 8);
      const unsigned short* vp = vbase + (size_t)(kt + 64 + sr)*768 + sc;
      vpa = *(const bf16x8*)vp; vpb = *(const bf16x8*)(vp + 8);
    }
    // S = Q K^T for 4 col-tiles of 16
    f32x4 sacc[4];
    #pragma unroll
    for (int ct = 0; ct < 4; ct++) {
      bf16x8 kf0 = *(bf16x8*)&Ks[ct*16 + lr][lg*8];
      bf16x8 kf1 = *(bf16x8*)&Ks[ct*16 + lr][32 + lg*8];
      f32x4 z = (f32x4){0.f,0.f,0.f,0.f};
      z = __builtin_amdgcn_mfma_f32_16x16x32_bf16(qf0, kf0, z, 0, 0, 0);
      z = __builtin_amdgcn_mfma_f32_16x16x32_bf16(qf1, kf1, z, 0, 0, 0);
      sacc[ct] = z;
    }
    // online softmax; lane holds rows lg*4+r at col lr (per ct)
    #pragma unroll
    for (int r = 0; r < 4; r++) {
      float s0 = sacc[0][r]*0.125f, s1 = sacc[1][r]*0.125f;
      float s2 = sacc[2][r]*0.125f, s3 = sacc[3][r]*0.125f;
      float rm = fmaxf(fmaxf(s0, s1), fmaxf(s2, s3));
      rm = fmaxf(rm, __shfl_xor(rm, 1));
      rm = fmaxf(rm, __shfl_xor(rm, 2));
      rm = fmaxf(rm, __shfl_xor(rm, 4));
      rm = fmaxf(rm, __shfl_xor(rm, 8));
      float mn = fmaxf(mrun[r], rm);
      float corr = __expf(mrun[r] - mn);
      float p0 = __expf(s0 - mn), p1 = __expf(s1 - mn);
      float p2 = __expf(s2 - mn), p3 = __expf(s3 - mn);
      float ps = p0 + p1 + p2 + p3;
      ps += __shfl_xor(ps, 1); ps += __shfl_xor(ps, 2);
      ps += __shfl_xor(ps, 4); ps += __shfl_xor(ps, 8);
      mrun[r] = mn;
      lrun[r] = lrun[r]*corr + ps;
      #pragma unroll
      for (int c = 0; c < 4; c++) oacc[c][r] *= corr;
      int prow = lg*4 + r;
      Ps[w][prow][ 0 + lr] = f2bf(p0);
      Ps[w][prow][16 + lr] = f2bf(p1);
      Ps[w][prow][32 + lr] = f2bf(p2);
      Ps[w][prow][48 + lr] = f2bf(p3);
    }
    // PV: A = P (rows=q, k=j), B = V via Vts[d][j]
    {
      bf16x8 pa0 = *(bf16x8*)&Ps[w][lr][lg*8];
      bf16x8 pa1 = *(bf16x8*)&Ps[w][lr][32 + lg*8];
      #pragma unroll
      for (int c = 0; c < 4; c++) {
        bf16x8 vf0 = *(bf16x8*)&Vts[c*16 + lr][lg*8];
        bf16x8 vf1 = *(bf16x8*)&Vts[c*16 + lr][32 + lg*8];
        oacc[c] = __builtin_amdgcn_mfma_f32_16x16x32_bf16(pa0, vf0, oacc[c], 0, 0, 0);
        oacc[c] = __builtin_amdgcn_mfma_f32_16x16x32_bf16(pa1, vf1, oacc[c], 0, 0, 0);
      }
    }
  }
  #pragma unroll
  for (int r = 0; r < 4; r++) {
    float inv = 1.0f / lrun[r];
    int row = q0 + w*16 + lg*4 + r;
    #pragma unroll
    for (int c = 0; c < 4; c++) {
      ctx[(size_t)row*DD + h*64 + c*16 + lr] = oacc[c][r] * inv;
    }
  }
}

// ---------------- gate ----------------
__global__ __launch_bounds__(256) void k_gate(
    const float* __restrict__ g1, const void* __restrict__ w2, const void* __restrict__ b2v,
    const int* __restrict__ flag,
    const float* __restrict__ agg, float* __restrict__ ag2)
{
  int i = blockIdx.x, t = threadIdx.x;
  int bfm = flag[0];
  __shared__ float red[256];
  red[t] = g1[(size_t)i*DD + t] * ldx(w2, t, bfm);
  __syncthreads();
  for (int k = 128; k > 0; k >>= 1) { if (t < k) red[t] += red[t + k]; __syncthreads(); }
  float sr = red[0] + ldx(b2v, 0, bfm);
  float s = 1.0f / (1.0f + __expf(-sr));
  ag2[(size_t)i*DD + t] = agg[(size_t)i*DD + t] * s;
}

extern "C" void kernel_launch(void* const* d_in, const int* in_sizes, int n_in,
                              void* d_out, int out_size, void* d_ws, size_t ws_size,
                              hipStream_t stream) {
  (void)in_sizes; (void)n_in; (void)out_size; (void)ws_size;
  const void* agent_states = d_in[0];
  const void* agent_emb    = d_in[1];
  const void* role_emb     = d_in[2];
  const void* gat_W        = d_in[3];
  const void* gat_att_src  = d_in[4];
  const void* gat_att_dst  = d_in[5];
  const void* gat_bias     = d_in[6];
  const void* ln_gamma     = d_in[7];
  const void* ln_beta      = d_in[8];
  const void* enc_W1 = d_in[9];
  const void* enc_b1 = d_in[10];
  const void* enc_W2 = d_in[11];
  const void* enc_b2 = d_in[12];
  const void* dec_W1 = d_in[13];
  const void* dec_b1 = d_in[14];
  const void* dec_W2 = d_in[15];
  const void* dec_b2 = d_in[16];
  const void* mha_in_w  = d_in[17];
  const void* mha_in_b  = d_in[18];
  const void* mha_out_w = d_in[19];
  const void* mha_out_b = d_in[20];
  const void* proj_W = d_in[21];
  const void* proj_b = d_in[22];
  const void* gate_W1 = d_in[23];
  const void* gate_b1 = d_in[24];
  const void* gate_W2 = d_in[25];
  const void* gate_b2 = d_in[26];

  char* base = (char*)d_ws;
  size_t off = 0;
  auto alloc = [&](size_t nbytes) -> char* {
    char* p = base + off; off += (nbytes + 255) & ~(size_t)255; return p;
  };
  int* flag = (int*)alloc(256);
  float* statesF = (float*)alloc((size_t)NA*DD*4);
  float* enh     = (float*)alloc((size_t)NA*DD*4);
  float* nsb     = (float*)alloc((size_t)NA*DD*4);
  unsigned long long* maskbits = (unsigned long long*)alloc((size_t)NA*64*8);
  float* xs  = (float*)alloc((size_t)NA*DD*4);
  float* xB  = (float*)alloc((size_t)NA*DD*4);
  bf16*  qkvb = (bf16*)alloc((size_t)NA*3*DD*2);
  float* dec = (float*)alloc((size_t)NA*DD*4);
  float* agg = (float*)alloc((size_t)NA*DD*4);
  float* candV = (float*)alloc((size_t)NA*20*4);
  int*   candI = (int*)alloc((size_t)NA*20*4);
  float* xC  = enh;
  float* aS  = nsb;
  float* aD  = nsb + NA*HH;
  float* h1  = nsb + 2*NA*HH;
  float* msg = h1 + (size_t)NA*64;
  float* dh  = msg + (size_t)NA*32;
  float* ctx = dec;           // dec free after qkv GEMM
  float* g1  = xs;
  float* ag2 = xB;

  auto gemm = [&](const float* A, const void* B, long boff, const void* bias, const float* resid,
                  float* Cf, void* Cb, int M, int Nn, int Kd, int act, int accF, int smode) {
    dim3 g((Nn + 63)/64, M/64);
    hipLaunchKernelGGL(k_gemm, g, dim3(256), 0, stream, A, B, boff, bias, resid, flag, Cf, Cb, M, Nn, Kd, act, accF, smode);
  };

  hipMemsetAsync(maskbits, 0, (size_t)NA*64*8, stream);
  hipLaunchKernelGGL(k_detect, dim3(1), dim3(256), 0, stream, agent_states, flag);
  hipLaunchKernelGGL(k_prep, dim3(NA), dim3(256), 0, stream,
                     agent_states, agent_emb, role_emb, flag, statesF, enh, nsb);
  hipLaunchKernelGGL(k_sim, dim3(NA/1024, NA/32), dim3(256), 0, stream, nsb, candV, candI);
  hipLaunchKernelGGL(k_topk, dim3(NA/256), dim3(256), 0, stream, candV, candI, maskbits);

  const float* xin = enh;
  float* xout = xB;
  for (int l = 0; l < LL; l++) {
    gemm(xin, gat_W, (long)l*DD*DD, nullptr, nullptr, xs, nullptr, NA, DD, DD, 0, 0, 0);
    hipLaunchKernelGGL(k_asd, dim3(NA), dim3(256), 0, stream,
                       xs, gat_att_src, gat_att_dst, (long)l*DD, flag, aS, aD);
    hipLaunchKernelGGL(k_gatagg, dim3(NA), dim3(256), 0, stream,
                       xs, aS, aD, maskbits, gat_bias, ln_gamma, ln_beta, (long)l*DD, flag, xin, xout);
    xin = xout; xout = xC;
  }
  gemm(xin, enc_W1, 0, enc_b1, nullptr, h1, nullptr, NA, 64, DD, 1, 0, 0);
  gemm(h1, enc_W2, 0, enc_b2, nullptr, msg, nullptr, NA, 32, 64, 0, 0, 0);
  gemm(msg, dec_W1, 0, dec_b1, nullptr, dh, nullptr, NA, 128, 32, 1, 0, 0);
  gemm(dh, dec_W2, 0, dec_b2, nullptr, dec, nullptr, NA, DD, 128, 0, 0, 0);
  gemm(dec, mha_in_w, 0, mha_in_b, nullptr, nullptr, qkvb, NA, 3*DD, DD, 0, 0, 1);
  hipLaunchKernelGGL(k_mha2, dim3(NA/64, HH), dim3(256), 0, stream, qkvb, ctx);
  gemm(ctx, mha_out_w, 0, mha_out_b, nullptr, agg, nullptr, NA, DD, DD, 0, 0, 0);
  gemm(statesF, gate_W1, 0, nullptr, nullptr, g1, nullptr, NA, DD, DD, 0, 0, 0);
  gemm(agg, gate_W1, (long)DD*DD, gate_b1, nullptr, g1, nullptr, NA, DD, DD, 1, 1, 0);
  hipLaunchKernelGGL(k_gate, dim3(NA), dim3(256), 0, stream, g1, gate_W2, gate_b2, flag, agg, ag2);
  gemm(ag2, proj_W, 0, proj_b, statesF, nullptr, d_out, NA, DD, DD, 0, 0, 2);
}